// Round 1
// baseline (738.923 us; speedup 1.0000x reference)
//
#include <hip/hip_runtime.h>
#include <hip/hip_bf16.h>

// ---------------- degree histogram ----------------
__global__ void deg_kernel(const int* __restrict__ dst, int* __restrict__ cnt, int E) {
    int e = blockIdx.x * 256 + threadIdx.x;
    if (e < E) atomicAdd(&cnt[dst[e]], 1);
}

// ---------------- hierarchical exclusive scan of (cnt[i]+1) -> rowptr ----------------
__global__ void scan1(const int* __restrict__ cnt, int* __restrict__ tmp,
                      int* __restrict__ bsum, int n) {
    __shared__ int s[256];
    int i = blockIdx.x * 256 + threadIdx.x;
    int v = (i < n) ? (cnt[i] + 1) : 0;
    s[threadIdx.x] = v;
    __syncthreads();
    for (int off = 1; off < 256; off <<= 1) {
        int x = (threadIdx.x >= off) ? s[threadIdx.x - off] : 0;
        __syncthreads();
        s[threadIdx.x] += x;
        __syncthreads();
    }
    if (i < n) tmp[i] = s[threadIdx.x];
    if (threadIdx.x == 255) bsum[blockIdx.x] = s[255];
}

__global__ void scan2(int* bsum, int nb) {
    __shared__ int s[256];
    int t = threadIdx.x;
    int v = (t < nb) ? bsum[t] : 0;
    s[t] = v;
    __syncthreads();
    for (int off = 1; off < 256; off <<= 1) {
        int x = (t >= off) ? s[t - off] : 0;
        __syncthreads();
        s[t] += x;
        __syncthreads();
    }
    if (t < nb) bsum[t] = s[t] - v;  // exclusive
}

__global__ void scan3(const int* __restrict__ tmp, const int* __restrict__ bsum,
                      int* __restrict__ rowptr, int n) {
    int i = blockIdx.x * 256 + threadIdx.x;
    if (i < n) rowptr[i + 1] = tmp[i] + bsum[blockIdx.x];
    if (i == 0) rowptr[0] = 0;
}

// ---------------- dinv + self-loop CSR entry ----------------
__global__ void dinv_selfloop(const int* __restrict__ cnt, const int* __restrict__ rowptr,
                              float* __restrict__ dinv, int* __restrict__ col, int n) {
    int i = blockIdx.x * 256 + threadIdx.x;
    if (i < n) {
        dinv[i] = rsqrtf((float)(cnt[i] + 1));
        col[rowptr[i]] = i;   // self-loop occupies slot 0 of each row
    }
}

// ---------------- fill CSR with real edges ----------------
__global__ void edgefill(const int* __restrict__ src, const int* __restrict__ dst,
                         const int* __restrict__ rowptr, int* __restrict__ fill,
                         int* __restrict__ col, int E) {
    int e = blockIdx.x * 256 + threadIdx.x;
    if (e < E) {
        int d = dst[e];
        int pos = rowptr[d] + 1 + atomicAdd(&fill[d], 1);
        col[pos] = src[e];
    }
}

// ---------------- fp32 GEMM: H[N,128] = X[N,128] @ W[128,128] ----------------
// block: 256 threads, 64 rows x 128 cols per block, each thread 8x4 outputs
__global__ __launch_bounds__(256) void gemm128(const float* __restrict__ X,
                                               const float* __restrict__ W,
                                               float* __restrict__ H, int Nrows) {
    __shared__ __align__(16) float xs[16][64];
    __shared__ __align__(16) float ws[16][128];
    int tid = threadIdx.x;
    int cx = tid & 31;   // col group -> cols 4*cx .. 4*cx+3
    int ry = tid >> 5;   // row group -> rows 8*ry .. 8*ry+7
    int row0 = blockIdx.x * 64;
    float acc[8][4] = {};
    for (int k0 = 0; k0 < 128; k0 += 16) {
        {   // stage X tile (transposed): xs[kk][r]
            int r = tid >> 2, j = (tid & 3) * 4;
            int gr = row0 + r;
            float4 v = make_float4(0.f, 0.f, 0.f, 0.f);
            if (gr < Nrows) v = *(const float4*)&X[gr * 128 + k0 + j];
            xs[j + 0][r] = v.x; xs[j + 1][r] = v.y; xs[j + 2][r] = v.z; xs[j + 3][r] = v.w;
        }
        {   // stage W tile: ws[kk][c], 2048 floats = 512 float4
            const float4* Wv = (const float4*)&W[k0 * 128];
            float4* wsv = (float4*)&ws[0][0];
            wsv[tid] = Wv[tid];
            wsv[tid + 256] = Wv[tid + 256];
        }
        __syncthreads();
#pragma unroll
        for (int kk = 0; kk < 16; ++kk) {
            float4 wv = *(float4*)&ws[kk][cx * 4];
            float4 xa = *(float4*)&xs[kk][ry * 8];
            float4 xb = *(float4*)&xs[kk][ry * 8 + 4];
            float xr[8] = {xa.x, xa.y, xa.z, xa.w, xb.x, xb.y, xb.z, xb.w};
#pragma unroll
            for (int i = 0; i < 8; ++i) {
                acc[i][0] += xr[i] * wv.x;
                acc[i][1] += xr[i] * wv.y;
                acc[i][2] += xr[i] * wv.z;
                acc[i][3] += xr[i] * wv.w;
            }
        }
        __syncthreads();
    }
#pragma unroll
    for (int i = 0; i < 8; ++i) {
        int gr = row0 + ry * 8 + i;
        if (gr < Nrows)
            *(float4*)&H[gr * 128 + cx * 4] =
                make_float4(acc[i][0], acc[i][1], acc[i][2], acc[i][3]);
    }
}

// ---------------- CSR aggregation: out[n] = relu?(dinv[n]*sum(dinv[s]*H[s]) + b) ----------------
// 256 threads = 2 nodes x 128 dims
__global__ __launch_bounds__(256) void agg_kernel(const float* __restrict__ H,
                                                  const float* __restrict__ dinv,
                                                  const int* __restrict__ rowptr,
                                                  const int* __restrict__ col,
                                                  const float* __restrict__ bias,
                                                  float* __restrict__ out,
                                                  int n, int relu) {
    int node = blockIdx.x * 2 + (threadIdx.x >> 7);
    int t = threadIdx.x & 127;
    if (node >= n) return;
    int beg = rowptr[node], end = rowptr[node + 1];
    float acc = 0.f;
    for (int k = beg; k < end; ++k) {
        int s = col[k];
        acc += H[s * 128 + t] * dinv[s];
    }
    float val = acc * dinv[node] + bias[t];
    if (relu) val = fmaxf(val, 0.f);
    out[node * 128 + t] = val;
}

// ---------------- edge decoder: out[e] = dot(X[u], X[v]) ----------------
__global__ __launch_bounds__(256) void decoder(const float* __restrict__ X,
                                               const int* __restrict__ eli,
                                               float* __restrict__ out, int EL) {
    int e = blockIdx.x * 4 + (threadIdx.x >> 6);
    int lane = threadIdx.x & 63;
    if (e >= EL) return;
    int u = eli[e], v = eli[EL + e];
    float2 a = *(const float2*)&X[u * 128 + lane * 2];
    float2 b = *(const float2*)&X[v * 128 + lane * 2];
    float d = a.x * b.x + a.y * b.y;
#pragma unroll
    for (int off = 32; off > 0; off >>= 1) d += __shfl_xor(d, off);
    if (lane == 0) out[e] = d;
}

extern "C" void kernel_launch(void* const* d_in, const int* in_sizes, int n_in,
                              void* d_out, int out_size, void* d_ws, size_t ws_size,
                              hipStream_t stream) {
    const float* x0 = (const float*)d_in[0];
    const float* W1 = (const float*)d_in[1];
    const float* b1 = (const float*)d_in[2];
    const float* W2 = (const float*)d_in[3];
    const float* b2 = (const float*)d_in[4];
    const float* W3 = (const float*)d_in[5];
    const float* b3 = (const float*)d_in[6];
    const int* ei   = (const int*)d_in[7];
    const int* eli  = (const int*)d_in[8];
    float* out = (float*)d_out;

    const int D = 128;
    const int N  = in_sizes[0] / D;
    const int E  = in_sizes[7] / 2;
    const int EL = in_sizes[8] / 2;

    const int* src = ei;        // edge_index[0]
    const int* dst = ei + E;    // edge_index[1]

    // -------- workspace carve-up (256B aligned) --------
    char* ws = (char*)d_ws;
    size_t off = 0;
    auto alloc = [&](size_t bytes) -> void* {
        off = (off + 255) & ~(size_t)255;
        void* p = ws + off;
        off += bytes;
        return p;
    };
    int*   cnt    = (int*)alloc((size_t)2 * N * sizeof(int)); // cnt + fill contiguous
    int*   fill   = cnt + N;
    int*   tmp    = (int*)alloc((size_t)N * sizeof(int));
    int*   bsum   = (int*)alloc(256 * sizeof(int));
    int*   rowptr = (int*)alloc((size_t)(N + 1) * sizeof(int));
    float* dinv   = (float*)alloc((size_t)N * sizeof(float));
    int*   col    = (int*)alloc((size_t)(E + N) * sizeof(int));
    float* hbuf   = (float*)alloc((size_t)N * D * sizeof(float));
    float* xbuf   = (float*)alloc((size_t)N * D * sizeof(float));
    (void)ws_size;

    // zero the two atomic-counter arrays
    hipMemsetAsync(cnt, 0, (size_t)2 * N * sizeof(int), stream);

    int nbN = (N + 255) / 256;
    int nbE = (E + 255) / 256;

    // ---- build degree / dinv / CSR ----
    deg_kernel<<<nbE, 256, 0, stream>>>(dst, cnt, E);
    scan1<<<nbN, 256, 0, stream>>>(cnt, tmp, bsum, N);
    scan2<<<1, 256, 0, stream>>>(bsum, nbN);
    scan3<<<nbN, 256, 0, stream>>>(tmp, bsum, rowptr, N);
    dinv_selfloop<<<nbN, 256, 0, stream>>>(cnt, rowptr, dinv, col, N);
    edgefill<<<nbE, 256, 0, stream>>>(src, dst, rowptr, fill, col, E);

    int gemmGrid = (N + 63) / 64;
    int aggGrid  = (N + 1) / 2;

    // ---- layer 1 ----
    gemm128<<<gemmGrid, 256, 0, stream>>>(x0, W1, hbuf, N);
    agg_kernel<<<aggGrid, 256, 0, stream>>>(hbuf, dinv, rowptr, col, b1, xbuf, N, 1);
    // ---- layer 2 ----
    gemm128<<<gemmGrid, 256, 0, stream>>>(xbuf, W2, hbuf, N);
    agg_kernel<<<aggGrid, 256, 0, stream>>>(hbuf, dinv, rowptr, col, b2, xbuf, N, 1);
    // ---- layer 3 ----
    gemm128<<<gemmGrid, 256, 0, stream>>>(xbuf, W3, hbuf, N);
    agg_kernel<<<aggGrid, 256, 0, stream>>>(hbuf, dinv, rowptr, col, b3, xbuf, N, 0);

    // ---- decoder ----
    decoder<<<(EL + 3) / 4, 256, 0, stream>>>(xbuf, eli, out, EL);
}

// Round 2
// 450.120 us; speedup vs baseline: 1.6416x; 1.6416x over previous
//
#include <hip/hip_runtime.h>
#include <hip/hip_bf16.h>

// ---------------- degree histogram ----------------
__global__ void deg_kernel(const int* __restrict__ dst, int* __restrict__ cnt, int E) {
    int e = blockIdx.x * 256 + threadIdx.x;
    if (e < E) atomicAdd(&cnt[dst[e]], 1);
}

// ---------------- hierarchical exclusive scan of (cnt[i]+1) -> rowptr ----------------
__global__ void scan1(const int* __restrict__ cnt, int* __restrict__ tmp,
                      int* __restrict__ bsum, int n) {
    __shared__ int s[256];
    int i = blockIdx.x * 256 + threadIdx.x;
    int v = (i < n) ? (cnt[i] + 1) : 0;
    s[threadIdx.x] = v;
    __syncthreads();
    for (int off = 1; off < 256; off <<= 1) {
        int x = (threadIdx.x >= off) ? s[threadIdx.x - off] : 0;
        __syncthreads();
        s[threadIdx.x] += x;
        __syncthreads();
    }
    if (i < n) tmp[i] = s[threadIdx.x];
    if (threadIdx.x == 255) bsum[blockIdx.x] = s[255];
}

__global__ void scan2(int* bsum, int nb) {
    __shared__ int s[256];
    int t = threadIdx.x;
    int v = (t < nb) ? bsum[t] : 0;
    s[t] = v;
    __syncthreads();
    for (int off = 1; off < 256; off <<= 1) {
        int x = (t >= off) ? s[t - off] : 0;
        __syncthreads();
        s[t] += x;
        __syncthreads();
    }
    if (t < nb) bsum[t] = s[t] - v;  // exclusive
}

__global__ void scan3(const int* __restrict__ tmp, const int* __restrict__ bsum,
                      int* __restrict__ rowptr, int n) {
    int i = blockIdx.x * 256 + threadIdx.x;
    if (i < n) rowptr[i + 1] = tmp[i] + bsum[blockIdx.x];
    if (i == 0) rowptr[0] = 0;
}

// ---------------- dinv + self-loop CSR entry ----------------
__global__ void dinv_selfloop(const int* __restrict__ cnt, const int* __restrict__ rowptr,
                              float* __restrict__ dinv, int* __restrict__ col, int n) {
    int i = blockIdx.x * 256 + threadIdx.x;
    if (i < n) {
        dinv[i] = rsqrtf((float)(cnt[i] + 1));
        col[rowptr[i]] = i;   // self-loop occupies slot 0 of each row
    }
}

// ---------------- fill CSR with real edges ----------------
__global__ void edgefill(const int* __restrict__ src, const int* __restrict__ dst,
                         const int* __restrict__ rowptr, int* __restrict__ fill,
                         int* __restrict__ col, int E) {
    int e = blockIdx.x * 256 + threadIdx.x;
    if (e < E) {
        int d = dst[e];
        int pos = rowptr[d] + 1 + atomicAdd(&fill[d], 1);
        col[pos] = src[e];
    }
}

// ---------------- fp32 GEMM: H[N,128] = (X[N,128] @ W[128,128]) * dscale[row] ----------------
// block: 256 threads, 64 rows x 128 cols per block, each thread 8x4 outputs.
// dinv row-scale folded into the epilogue so the agg inner loop is a pure sum.
__global__ __launch_bounds__(256) void gemm128(const float* __restrict__ X,
                                               const float* __restrict__ W,
                                               const float* __restrict__ dscale,
                                               float* __restrict__ H, int Nrows) {
    __shared__ __align__(16) float xs[16][64];
    __shared__ __align__(16) float ws[16][128];
    int tid = threadIdx.x;
    int cx = tid & 31;   // col group -> cols 4*cx .. 4*cx+3
    int ry = tid >> 5;   // row group -> rows 8*ry .. 8*ry+7
    int row0 = blockIdx.x * 64;
    float acc[8][4] = {};
    for (int k0 = 0; k0 < 128; k0 += 16) {
        {   // stage X tile (transposed): xs[kk][r]
            int r = tid >> 2, j = (tid & 3) * 4;
            int gr = row0 + r;
            float4 v = make_float4(0.f, 0.f, 0.f, 0.f);
            if (gr < Nrows) v = *(const float4*)&X[gr * 128 + k0 + j];
            xs[j + 0][r] = v.x; xs[j + 1][r] = v.y; xs[j + 2][r] = v.z; xs[j + 3][r] = v.w;
        }
        {   // stage W tile: ws[kk][c], 2048 floats = 512 float4
            const float4* Wv = (const float4*)&W[k0 * 128];
            float4* wsv = (float4*)&ws[0][0];
            wsv[tid] = Wv[tid];
            wsv[tid + 256] = Wv[tid + 256];
        }
        __syncthreads();
#pragma unroll
        for (int kk = 0; kk < 16; ++kk) {
            float4 wv = *(float4*)&ws[kk][cx * 4];
            float4 xa = *(float4*)&xs[kk][ry * 8];
            float4 xb = *(float4*)&xs[kk][ry * 8 + 4];
            float xr[8] = {xa.x, xa.y, xa.z, xa.w, xb.x, xb.y, xb.z, xb.w};
#pragma unroll
            for (int i = 0; i < 8; ++i) {
                acc[i][0] += xr[i] * wv.x;
                acc[i][1] += xr[i] * wv.y;
                acc[i][2] += xr[i] * wv.z;
                acc[i][3] += xr[i] * wv.w;
            }
        }
        __syncthreads();
    }
#pragma unroll
    for (int i = 0; i < 8; ++i) {
        int gr = row0 + ry * 8 + i;
        if (gr < Nrows) {
            float s = dscale[gr];
            *(float4*)&H[gr * 128 + cx * 4] =
                make_float4(acc[i][0] * s, acc[i][1] * s, acc[i][2] * s, acc[i][3] * s);
        }
    }
}

// ---------------- CSR aggregation: out[n] = relu?(dinv[n]*sum(H'[s]) + b) ----------------
// H' is pre-scaled by dinv[row] in the GEMM epilogue.
// 256 threads = 8 nodes x 32 lanes; each lane holds 4 dims (float4).
// Unroll-by-4 with index prefetch -> 4 independent dwordx4 gathers in flight.
__global__ __launch_bounds__(256) void agg_kernel(const float* __restrict__ H,
                                                  const float* __restrict__ dinv,
                                                  const int* __restrict__ rowptr,
                                                  const int* __restrict__ col,
                                                  const float* __restrict__ bias,
                                                  float* __restrict__ out,
                                                  int n, int relu) {
    int node = blockIdx.x * 8 + (threadIdx.x >> 5);
    int t = (threadIdx.x & 31) * 4;
    if (node >= n) return;
    int beg = rowptr[node], end = rowptr[node + 1];
    float ax = 0.f, ay = 0.f, az = 0.f, aw = 0.f;
    int k = beg;
    for (; k + 4 <= end; k += 4) {
        int s0 = col[k], s1 = col[k + 1], s2 = col[k + 2], s3 = col[k + 3];
        float4 h0 = *(const float4*)&H[(size_t)s0 * 128 + t];
        float4 h1 = *(const float4*)&H[(size_t)s1 * 128 + t];
        float4 h2 = *(const float4*)&H[(size_t)s2 * 128 + t];
        float4 h3 = *(const float4*)&H[(size_t)s3 * 128 + t];
        ax += (h0.x + h1.x) + (h2.x + h3.x);
        ay += (h0.y + h1.y) + (h2.y + h3.y);
        az += (h0.z + h1.z) + (h2.z + h3.z);
        aw += (h0.w + h1.w) + (h2.w + h3.w);
    }
    for (; k < end; ++k) {
        float4 h = *(const float4*)&H[(size_t)col[k] * 128 + t];
        ax += h.x; ay += h.y; az += h.z; aw += h.w;
    }
    float dn = dinv[node];
    float4 bv = *(const float4*)&bias[t];
    float4 r = make_float4(ax * dn + bv.x, ay * dn + bv.y,
                           az * dn + bv.z, aw * dn + bv.w);
    if (relu) {
        r.x = fmaxf(r.x, 0.f); r.y = fmaxf(r.y, 0.f);
        r.z = fmaxf(r.z, 0.f); r.w = fmaxf(r.w, 0.f);
    }
    *(float4*)&out[(size_t)node * 128 + t] = r;
}

// ---------------- edge decoder: out[e] = dot(X[u], X[v]) ----------------
// 32 lanes per edge, float4 loads; 8 edges per 256-block.
__global__ __launch_bounds__(256) void decoder(const float* __restrict__ X,
                                               const int* __restrict__ eli,
                                               float* __restrict__ out, int EL) {
    int e = blockIdx.x * 8 + (threadIdx.x >> 5);
    int lane = threadIdx.x & 31;
    if (e >= EL) return;
    int u = eli[e], v = eli[EL + e];
    float4 a = *(const float4*)&X[(size_t)u * 128 + lane * 4];
    float4 b = *(const float4*)&X[(size_t)v * 128 + lane * 4];
    float d = a.x * b.x + a.y * b.y + a.z * b.z + a.w * b.w;
#pragma unroll
    for (int off = 16; off > 0; off >>= 1) d += __shfl_xor(d, off);
    if (lane == 0) out[e] = d;
}

extern "C" void kernel_launch(void* const* d_in, const int* in_sizes, int n_in,
                              void* d_out, int out_size, void* d_ws, size_t ws_size,
                              hipStream_t stream) {
    const float* x0 = (const float*)d_in[0];
    const float* W1 = (const float*)d_in[1];
    const float* b1 = (const float*)d_in[2];
    const float* W2 = (const float*)d_in[3];
    const float* b2 = (const float*)d_in[4];
    const float* W3 = (const float*)d_in[5];
    const float* b3 = (const float*)d_in[6];
    const int* ei   = (const int*)d_in[7];
    const int* eli  = (const int*)d_in[8];
    float* out = (float*)d_out;

    const int D = 128;
    const int N  = in_sizes[0] / D;
    const int E  = in_sizes[7] / 2;
    const int EL = in_sizes[8] / 2;

    const int* src = ei;        // edge_index[0]
    const int* dst = ei + E;    // edge_index[1]

    // -------- workspace carve-up (256B aligned) --------
    char* ws = (char*)d_ws;
    size_t off = 0;
    auto alloc = [&](size_t bytes) -> void* {
        off = (off + 255) & ~(size_t)255;
        void* p = ws + off;
        off += bytes;
        return p;
    };
    int*   cnt    = (int*)alloc((size_t)2 * N * sizeof(int)); // cnt + fill contiguous
    int*   fill   = cnt + N;
    int*   tmp    = (int*)alloc((size_t)N * sizeof(int));
    int*   bsum   = (int*)alloc(256 * sizeof(int));
    int*   rowptr = (int*)alloc((size_t)(N + 1) * sizeof(int));
    float* dinv   = (float*)alloc((size_t)N * sizeof(float));
    int*   col    = (int*)alloc((size_t)(E + N) * sizeof(int));
    float* hbuf   = (float*)alloc((size_t)N * D * sizeof(float));
    float* xbuf   = (float*)alloc((size_t)N * D * sizeof(float));
    (void)ws_size;

    // zero the two atomic-counter arrays
    hipMemsetAsync(cnt, 0, (size_t)2 * N * sizeof(int), stream);

    int nbN = (N + 255) / 256;
    int nbE = (E + 255) / 256;

    // ---- build degree / dinv / CSR ----
    deg_kernel<<<nbE, 256, 0, stream>>>(dst, cnt, E);
    scan1<<<nbN, 256, 0, stream>>>(cnt, tmp, bsum, N);
    scan2<<<1, 256, 0, stream>>>(bsum, nbN);
    scan3<<<nbN, 256, 0, stream>>>(tmp, bsum, rowptr, N);
    dinv_selfloop<<<nbN, 256, 0, stream>>>(cnt, rowptr, dinv, col, N);
    edgefill<<<nbE, 256, 0, stream>>>(src, dst, rowptr, fill, col, E);

    int gemmGrid = (N + 63) / 64;
    int aggGrid  = (N + 7) / 8;

    // ---- layer 1 ----
    gemm128<<<gemmGrid, 256, 0, stream>>>(x0, W1, dinv, hbuf, N);
    agg_kernel<<<aggGrid, 256, 0, stream>>>(hbuf, dinv, rowptr, col, b1, xbuf, N, 1);
    // ---- layer 2 ----
    gemm128<<<gemmGrid, 256, 0, stream>>>(xbuf, W2, dinv, hbuf, N);
    agg_kernel<<<aggGrid, 256, 0, stream>>>(hbuf, dinv, rowptr, col, b2, xbuf, N, 1);
    // ---- layer 3 ----
    gemm128<<<gemmGrid, 256, 0, stream>>>(xbuf, W3, dinv, hbuf, N);
    agg_kernel<<<aggGrid, 256, 0, stream>>>(hbuf, dinv, rowptr, col, b3, xbuf, N, 0);

    // ---- decoder ----
    decoder<<<(EL + 7) / 8, 256, 0, stream>>>(xbuf, eli, out, EL);
}

// Round 3
// 449.843 us; speedup vs baseline: 1.6426x; 1.0006x over previous
//
#include <hip/hip_runtime.h>
#include <hip/hip_bf16.h>

// ---------------- degree histogram ----------------
__global__ void deg_kernel(const int* __restrict__ dst, int* __restrict__ cnt, int E) {
    int e = blockIdx.x * 256 + threadIdx.x;
    if (e < E) atomicAdd(&cnt[dst[e]], 1);
}

// ---------------- hierarchical exclusive scan of (cnt[i]+1) -> rowptr ----------------
__global__ void scan1(const int* __restrict__ cnt, int* __restrict__ tmp,
                      int* __restrict__ bsum, int n) {
    __shared__ int s[256];
    int i = blockIdx.x * 256 + threadIdx.x;
    int v = (i < n) ? (cnt[i] + 1) : 0;
    s[threadIdx.x] = v;
    __syncthreads();
    for (int off = 1; off < 256; off <<= 1) {
        int x = (threadIdx.x >= off) ? s[threadIdx.x - off] : 0;
        __syncthreads();
        s[threadIdx.x] += x;
        __syncthreads();
    }
    if (i < n) tmp[i] = s[threadIdx.x];
    if (threadIdx.x == 255) bsum[blockIdx.x] = s[255];
}

__global__ void scan2(int* bsum, int nb) {
    __shared__ int s[256];
    int t = threadIdx.x;
    int v = (t < nb) ? bsum[t] : 0;
    s[t] = v;
    __syncthreads();
    for (int off = 1; off < 256; off <<= 1) {
        int x = (t >= off) ? s[t - off] : 0;
        __syncthreads();
        s[t] += x;
        __syncthreads();
    }
    if (t < nb) bsum[t] = s[t] - v;  // exclusive
}

// scan3 fused with dinv + self-loop CSR entry
__global__ void scan3(const int* __restrict__ tmp, const int* __restrict__ bsum,
                      const int* __restrict__ cnt, int* __restrict__ rowptr,
                      float* __restrict__ dinv, int* __restrict__ col, int n) {
    int i = blockIdx.x * 256 + threadIdx.x;
    if (i < n) {
        int inc = tmp[i] + bsum[blockIdx.x];   // inclusive scan of (cnt+1)
        rowptr[i + 1] = inc;
        int c1 = cnt[i] + 1;
        int r0 = inc - c1;                     // exclusive = rowptr[i]
        dinv[i] = rsqrtf((float)c1);
        col[r0] = i;                           // self-loop occupies slot 0 of row i
        if (i == 0) rowptr[0] = 0;
    }
}

// ---------------- fill CSR with real edges ----------------
__global__ void edgefill(const int* __restrict__ src, const int* __restrict__ dst,
                         const int* __restrict__ rowptr, int* __restrict__ fill,
                         int* __restrict__ col, int E) {
    int e = blockIdx.x * 256 + threadIdx.x;
    if (e < E) {
        int d = dst[e];
        int pos = rowptr[d] + 1 + atomicAdd(&fill[d], 1);
        col[pos] = src[e];
    }
}

// ---------------- fp32 GEMM: H[N,128] = (X[N,128] @ W[128,128]) * dscale[row] ----------------
// block: 256 threads, 64 rows x 128 cols per block, each thread 8x4 outputs.
// xs padded to 68: staging stores drop from 4-way to 2-way (free) bank aliasing.
__global__ __launch_bounds__(256) void gemm128(const float* __restrict__ X,
                                               const float* __restrict__ W,
                                               const float* __restrict__ dscale,
                                               float* __restrict__ H, int Nrows) {
    __shared__ __align__(16) float xs[16][68];
    __shared__ __align__(16) float ws[16][128];
    int tid = threadIdx.x;
    int cx = tid & 31;   // col group -> cols 4*cx .. 4*cx+3
    int ry = tid >> 5;   // row group -> rows 8*ry .. 8*ry+7
    int row0 = blockIdx.x * 64;
    float acc[8][4] = {};
    for (int k0 = 0; k0 < 128; k0 += 16) {
        {   // stage X tile (transposed): xs[kk][r]
            int r = tid >> 2, j = (tid & 3) * 4;
            int gr = row0 + r;
            float4 v = make_float4(0.f, 0.f, 0.f, 0.f);
            if (gr < Nrows) v = *(const float4*)&X[gr * 128 + k0 + j];
            xs[j + 0][r] = v.x; xs[j + 1][r] = v.y; xs[j + 2][r] = v.z; xs[j + 3][r] = v.w;
        }
        {   // stage W tile: ws[kk][c], 2048 floats = 512 float4
            const float4* Wv = (const float4*)&W[k0 * 128];
            float4* wsv = (float4*)&ws[0][0];
            wsv[tid] = Wv[tid];
            wsv[tid + 256] = Wv[tid + 256];
        }
        __syncthreads();
#pragma unroll
        for (int kk = 0; kk < 16; ++kk) {
            float4 wv = *(float4*)&ws[kk][cx * 4];
            float4 xa = *(float4*)&xs[kk][ry * 8];
            float4 xb = *(float4*)&xs[kk][ry * 8 + 4];
            float xr[8] = {xa.x, xa.y, xa.z, xa.w, xb.x, xb.y, xb.z, xb.w};
#pragma unroll
            for (int i = 0; i < 8; ++i) {
                acc[i][0] += xr[i] * wv.x;
                acc[i][1] += xr[i] * wv.y;
                acc[i][2] += xr[i] * wv.z;
                acc[i][3] += xr[i] * wv.w;
            }
        }
        __syncthreads();
    }
#pragma unroll
    for (int i = 0; i < 8; ++i) {
        int gr = row0 + ry * 8 + i;
        if (gr < Nrows) {
            float s = dscale[gr];
            *(float4*)&H[gr * 128 + cx * 4] =
                make_float4(acc[i][0] * s, acc[i][1] * s, acc[i][2] * s, acc[i][3] * s);
        }
    }
}

// ---------------- CSR aggregation: out[n] = relu?(dinv[n]*sum(H'[s]) + b) ----------------
// H' is pre-scaled by dinv[row] in the GEMM epilogue.
// 256 threads = 8 nodes x 32 lanes; each lane holds 4 dims (float4).
// Unroll-by-8 with clamped indices -> 8 independent dwordx4 gathers in flight;
// clamped duplicates hit L1, predicated accumulate keeps the sum exact.
__global__ __launch_bounds__(256) void agg_kernel(const float* __restrict__ H,
                                                  const float* __restrict__ dinv,
                                                  const int* __restrict__ rowptr,
                                                  const int* __restrict__ col,
                                                  const float* __restrict__ bias,
                                                  float* __restrict__ out,
                                                  int n, int relu) {
    int node = blockIdx.x * 8 + (threadIdx.x >> 5);
    int t = (threadIdx.x & 31) * 4;
    if (node >= n) return;
    int beg = rowptr[node], end = rowptr[node + 1];
    float ax = 0.f, ay = 0.f, az = 0.f, aw = 0.f;
    for (int k = beg; k < end; k += 8) {
        int idx[8];
#pragma unroll
        for (int j = 0; j < 8; ++j) {
            int kj = k + j;
            idx[j] = col[kj < end ? kj : end - 1];
        }
        float4 h[8];
#pragma unroll
        for (int j = 0; j < 8; ++j)
            h[j] = *(const float4*)&H[(size_t)idx[j] * 128 + t];
#pragma unroll
        for (int j = 0; j < 8; ++j) {
            if (k + j < end) {
                ax += h[j].x; ay += h[j].y; az += h[j].z; aw += h[j].w;
            }
        }
    }
    float dn = dinv[node];
    float4 bv = *(const float4*)&bias[t];
    float4 r = make_float4(ax * dn + bv.x, ay * dn + bv.y,
                           az * dn + bv.z, aw * dn + bv.w);
    if (relu) {
        r.x = fmaxf(r.x, 0.f); r.y = fmaxf(r.y, 0.f);
        r.z = fmaxf(r.z, 0.f); r.w = fmaxf(r.w, 0.f);
    }
    *(float4*)&out[(size_t)node * 128 + t] = r;
}

// ---------------- edge decoder: out[e] = dot(X[u], X[v]) ----------------
// 16 lanes per edge, 8 floats per lane (2x float4) -> 4 gathers in flight/lane.
__global__ __launch_bounds__(256) void decoder(const float* __restrict__ X,
                                               const int* __restrict__ eli,
                                               float* __restrict__ out, int EL) {
    int e = blockIdx.x * 16 + (threadIdx.x >> 4);
    int lane = threadIdx.x & 15;
    if (e >= EL) return;
    int u = eli[e], v = eli[EL + e];
    const float4* Xu = (const float4*)&X[(size_t)u * 128 + lane * 8];
    const float4* Xv = (const float4*)&X[(size_t)v * 128 + lane * 8];
    float4 a0 = Xu[0], a1 = Xu[1];
    float4 b0 = Xv[0], b1 = Xv[1];
    float d = a0.x * b0.x + a0.y * b0.y + a0.z * b0.z + a0.w * b0.w
            + a1.x * b1.x + a1.y * b1.y + a1.z * b1.z + a1.w * b1.w;
#pragma unroll
    for (int off = 8; off > 0; off >>= 1) d += __shfl_xor(d, off);
    if (lane == 0) out[e] = d;
}

extern "C" void kernel_launch(void* const* d_in, const int* in_sizes, int n_in,
                              void* d_out, int out_size, void* d_ws, size_t ws_size,
                              hipStream_t stream) {
    const float* x0 = (const float*)d_in[0];
    const float* W1 = (const float*)d_in[1];
    const float* b1 = (const float*)d_in[2];
    const float* W2 = (const float*)d_in[3];
    const float* b2 = (const float*)d_in[4];
    const float* W3 = (const float*)d_in[5];
    const float* b3 = (const float*)d_in[6];
    const int* ei   = (const int*)d_in[7];
    const int* eli  = (const int*)d_in[8];
    float* out = (float*)d_out;

    const int D = 128;
    const int N  = in_sizes[0] / D;
    const int E  = in_sizes[7] / 2;
    const int EL = in_sizes[8] / 2;

    const int* src = ei;        // edge_index[0]
    const int* dst = ei + E;    // edge_index[1]

    // -------- workspace carve-up (256B aligned) --------
    char* ws = (char*)d_ws;
    size_t off = 0;
    auto alloc = [&](size_t bytes) -> void* {
        off = (off + 255) & ~(size_t)255;
        void* p = ws + off;
        off += bytes;
        return p;
    };
    int*   cnt    = (int*)alloc((size_t)2 * N * sizeof(int)); // cnt + fill contiguous
    int*   fill   = cnt + N;
    int*   tmp    = (int*)alloc((size_t)N * sizeof(int));
    int*   bsum   = (int*)alloc(256 * sizeof(int));
    int*   rowptr = (int*)alloc((size_t)(N + 1) * sizeof(int));
    float* dinv   = (float*)alloc((size_t)N * sizeof(float));
    int*   col    = (int*)alloc((size_t)(E + N) * sizeof(int));
    float* hbuf   = (float*)alloc((size_t)N * D * sizeof(float));
    float* xbuf   = (float*)alloc((size_t)N * D * sizeof(float));
    (void)ws_size;

    // zero the two atomic-counter arrays
    hipMemsetAsync(cnt, 0, (size_t)2 * N * sizeof(int), stream);

    int nbN = (N + 255) / 256;
    int nbE = (E + 255) / 256;

    // ---- build degree / dinv / CSR ----
    deg_kernel<<<nbE, 256, 0, stream>>>(dst, cnt, E);
    scan1<<<nbN, 256, 0, stream>>>(cnt, tmp, bsum, N);
    scan2<<<1, 256, 0, stream>>>(bsum, nbN);
    scan3<<<nbN, 256, 0, stream>>>(tmp, bsum, cnt, rowptr, dinv, col, N);
    edgefill<<<nbE, 256, 0, stream>>>(src, dst, rowptr, fill, col, E);

    int gemmGrid = (N + 63) / 64;
    int aggGrid  = (N + 7) / 8;

    // ---- layer 1 ----
    gemm128<<<gemmGrid, 256, 0, stream>>>(x0, W1, dinv, hbuf, N);
    agg_kernel<<<aggGrid, 256, 0, stream>>>(hbuf, dinv, rowptr, col, b1, xbuf, N, 1);
    // ---- layer 2 ----
    gemm128<<<gemmGrid, 256, 0, stream>>>(xbuf, W2, dinv, hbuf, N);
    agg_kernel<<<aggGrid, 256, 0, stream>>>(hbuf, dinv, rowptr, col, b2, xbuf, N, 1);
    // ---- layer 3 ----
    gemm128<<<gemmGrid, 256, 0, stream>>>(xbuf, W3, dinv, hbuf, N);
    agg_kernel<<<aggGrid, 256, 0, stream>>>(hbuf, dinv, rowptr, col, b3, xbuf, N, 0);

    // ---- decoder ----
    decoder<<<(EL + 15) / 16, 256, 0, stream>>>(xbuf, eli, out, EL);
}